// Round 2
// baseline (1775.760 us; speedup 1.0000x reference)
//
#include <hip/hip_runtime.h>
#include <hip/hip_bf16.h>

// Grouped GEMM (FMoE expert linear), MI355X/gfx950.
// out[t,n] = sum_k inp[t,k] * weight[e(t),n,k] + bias[e(t),n]
// T=8192, K=2048, N=8192, E=16, equal 512-token groups.
//
// R2: two-kernel plan.
//  (1) convert_bf16: fp32 -> bf16 into d_ws, laid out as ready-made 256x64
//      LDS tile images with the XOR bank-swizzle (byte ^= (row&7)<<4) baked in.
//  (2) moe_gemm: 256x256xBK64 bf16 GEMM, staging = pure global_load_lds_dwordx4
//      (no reg round-trip, no conversion VALU, no ds_write in the hot loop),
//      one __syncthreads per K=64, conflict-free swizzled ds_read_b128.
// R1 post-mortem: tile-size change was neutral -> bottleneck is the fp32
// reg-staging + convert path, not HBM traffic. This removes it.

#define TOK   8192
#define KDIM  2048
#define NDIM  8192
#define NEXP  16

#define BM 256
#define BN 256
#define BK 64
#define NKT (KDIM / BK)                  // 32 k-tiles
#define NMT (TOK / BM)                   // 32 m-tiles
#define NNT (NDIM / BN)                  // 32 n-tiles
#define TILE_BYTES (256 * BK * 2)        // 32768 B per 256x64 bf16 tile

#define WSA_BYTES ((size_t)NMT * NKT * TILE_BYTES)          // 33.5 MB
#define WSB_OFF   0x2800000ull                              // 41.9 MB (>= WSA)
#define WSB_BYTES ((size_t)NEXP * NNT * NKT * TILE_BYTES)   // 537 MB
#define WS_NEED   (WSB_OFF + WSB_BYTES)                     // ~579 MB

typedef __attribute__((ext_vector_type(8))) short short8;
typedef __attribute__((ext_vector_type(4))) float f32x4;

// fp32 -> bf16 (round-half-up) pair pack: 1 add per elem + 1 v_perm per pair.
__device__ __forceinline__ unsigned pk2(float lo, float hi) {
    unsigned ul = __float_as_uint(lo) + 0x8000u;
    unsigned uh = __float_as_uint(hi) + 0x8000u;
    return __builtin_amdgcn_perm(uh, ul, 0x07060302u);
}
__device__ __forceinline__ uint2 pk4(float4 v) {
    uint2 r;
    r.x = pk2(v.x, v.y);
    r.y = pk2(v.z, v.w);
    return r;
}

// ---------------------------------------------------------------------------
// Kernel 1: fp32 -> bf16 tiler. One block per source row (8 KB, perfectly
// coalesced read by 256 threads); each thread emits one 16B chunk (8 bf16)
// at its swizzled position inside the destination tile image.
// rows [0, TOK)               -> A tiles  (mt, kt), tile row = token & 255
// rows [TOK, TOK+E*NDIM)      -> B tiles  (e, nt, kt), tile row = n & 255
// swizzled offset inside tile: row*128 + ((cg*16) ^ ((row&7)<<4))
// ---------------------------------------------------------------------------
__global__ __launch_bounds__(256) void convert_bf16(
    const float* __restrict__ inp,
    const float* __restrict__ weight,
    char*        __restrict__ ws)
{
    const int row = blockIdx.x;          // 0 .. TOK + NEXP*NDIM - 1
    const int t   = threadIdx.x;         // 0..255
    const int kt  = t >> 3;              // 0..31
    const int cg  = t & 7;               // 0..7 (16B chunk within 64-col tile row)

    const float4* src;
    size_t dst;
    if (row < TOK) {
        src = (const float4*)(inp + (size_t)row * KDIM + t * 8);
        const int mt = row >> 8, r = row & 255;
        dst = (size_t)(mt * NKT + kt) * TILE_BYTES
            + r * 128 + ((cg * 16) ^ ((r & 7) << 4));
    } else {
        const int rr = row - TOK;                 // e*8192 + n
        src = (const float4*)(weight + (size_t)rr * KDIM + t * 8);
        const int e = rr >> 13, n = rr & 8191;
        const int nt = n >> 8, r = n & 255;
        dst = WSB_OFF
            + (size_t)((e * NNT + nt) * NKT + kt) * TILE_BYTES
            + r * 128 + ((cg * 16) ^ ((r & 7) << 4));
    }
    float4 v0 = src[0], v1 = src[1];
    uint2 p0 = pk4(v0), p1 = pk4(v1);
    uint4 o; o.x = p0.x; o.y = p0.y; o.z = p1.x; o.w = p1.y;
    *(uint4*)(ws + dst) = o;
}

// ---------------------------------------------------------------------------
// Kernel 2: bf16 grouped GEMM. 1024 blocks, 512 threads (8 waves, 2m x 4n),
// wave tile 128x64, acc[8][4]. Double-buffered 2x(32+32) KB LDS = 128 KB.
// Staging: 8x global_load_lds_dwordx4 per thread per K-tile (verbatim copy of
// the pre-swizzled tile image). One __syncthreads per K-tile.
// ---------------------------------------------------------------------------
__global__ __launch_bounds__(512) void moe_gemm(
    const char*  __restrict__ ws,
    const float* __restrict__ bias,
    const int*   __restrict__ cnt,
    float*       __restrict__ out)
{
    __shared__ __attribute__((aligned(16))) char lds[2][2][TILE_BYTES]; // 128 KB

    const int tid = threadIdx.x;
    const int b   = blockIdx.x;

    // XCD-aware swizzle over 1024 blocks = 8 xcd * (16 e * 4 nl * 2 mi);
    // m innermost so the 2 m-blocks sharing a weight panel are dispatch-adjacent.
    const int x  = b & 7;
    const int j  = b >> 3;
    const int e  = j >> 3;
    const int t  = j & 7;
    const int nl = t >> 1;
    const int mi = t & 1;
    const int ntile = x * 4 + nl;    // 0..31

    int m_start = 0;
    for (int i = 0; i < e; ++i) m_start += cnt[i];
    const int m0 = m_start + mi * BM;      // harness: 512/expert, 256-aligned
    const int n0 = ntile * BN;

    const char* gA = ws + (size_t)((m0 >> 8) * NKT) * TILE_BYTES + tid * 16;
    const char* gB = ws + WSB_OFF
                   + (size_t)((e * NNT + (n0 >> 8)) * NKT) * TILE_BYTES + tid * 16;

#define STAGE(c, kt_) do {                                                    \
    const char* _a = gA + (size_t)(kt_) * TILE_BYTES;                         \
    const char* _b = gB + (size_t)(kt_) * TILE_BYTES;                         \
    _Pragma("unroll")                                                         \
    for (int _i = 0; _i < 4; ++_i) {                                          \
        __builtin_amdgcn_global_load_lds(                                     \
            (const __attribute__((address_space(1))) unsigned int*)(_a + _i * 8192), \
            (__attribute__((address_space(3))) unsigned int*)(&lds[c][0][tid * 16] + _i * 8192), \
            16, 0, 0);                                                        \
        __builtin_amdgcn_global_load_lds(                                     \
            (const __attribute__((address_space(1))) unsigned int*)(_b + _i * 8192), \
            (__attribute__((address_space(3))) unsigned int*)(&lds[c][1][tid * 16] + _i * 8192), \
            16, 0, 0);                                                        \
    }                                                                         \
} while (0)

    // wave mapping: 8 waves in 2(m) x 4(n), each computes 128x64 (8x4 of 16x16)
    const int wave = tid >> 6;
    const int lane = tid & 63;
    const int wm   = wave & 1;
    const int wn   = wave >> 1;
    const int r16  = lane & 15;
    const int quad = lane >> 4;
    const int swz  = (r16 & 7) << 4;

    f32x4 acc[8][4] = {};

    STAGE(0, 0);
    __syncthreads();   // drains vmcnt -> tile 0 resident

    int cur = 0;
    for (int kt = 0; kt < NKT; ++kt) {
        if (kt + 1 < NKT) STAGE(cur ^ 1, kt + 1);   // prefetch flies over MFMA

        const char* la = &lds[cur][0][0] + (size_t)(wm * 128 + r16) * 128;
        const char* lb = &lds[cur][1][0] + (size_t)(wn * 64  + r16) * 128;

        #pragma unroll
        for (int kk = 0; kk < 2; ++kk) {
            const int koff = (kk * 64 + quad * 16) ^ swz;
            short8 bfr[4];
            #pragma unroll
            for (int nt = 0; nt < 4; ++nt)
                bfr[nt] = *(const short8*)(lb + nt * (16 * 128) + koff);
            #pragma unroll
            for (int mt = 0; mt < 8; ++mt) {
                const short8 af = *(const short8*)(la + mt * (16 * 128) + koff);
                #pragma unroll
                for (int nt = 0; nt < 4; ++nt)
                    acc[mt][nt] = __builtin_amdgcn_mfma_f32_16x16x32_bf16(
                        af, bfr[nt], acc[mt][nt], 0, 0, 0);
            }
        }
        __syncthreads();   // readers done with lds[cur]; prefetch landed
        cur ^= 1;
    }

    // epilogue: C/D layout col=lane&15 (n), row=quad*4+reg (m); add bias
    #pragma unroll
    for (int nt = 0; nt < 4; ++nt) {
        const int n = n0 + wn * 64 + nt * 16 + r16;
        const float bv = bias[(size_t)e * NDIM + n];
        #pragma unroll
        for (int mt = 0; mt < 8; ++mt) {
            #pragma unroll
            for (int r = 0; r < 4; ++r) {
                const int m = m0 + wm * 128 + mt * 16 + quad * 4 + r;
                out[(size_t)m * NDIM + n] = acc[mt][nt][r] + bv;
            }
        }
    }
#undef STAGE
}

// ---------------------------------------------------------------------------
// Fallback (ws too small): R1 kernel — fp32 reg-staged 256x256x32.
// ---------------------------------------------------------------------------
#define LDSS 40
__global__ __launch_bounds__(512) void moe_gemm_fb(
    const float* __restrict__ inp,
    const float* __restrict__ weight,
    const float* __restrict__ bias,
    const int*   __restrict__ cnt,
    float*       __restrict__ out)
{
    __shared__ short sA[BM * LDSS];
    __shared__ short sB[BN * LDSS];

    const int tid = threadIdx.x;
    const int b   = blockIdx.x;
    const int x  = b & 7;
    const int j  = b >> 3;
    const int e  = j >> 3;
    const int t  = j & 7;
    const int nl = t >> 1;
    const int mi = t & 1;
    const int ntile = x * 4 + nl;

    int m_start = 0;
    for (int i = 0; i < e; ++i) m_start += cnt[i];
    const int m0 = m_start + mi * BM;
    const int n0 = ntile * BN;

    const float* wexp = weight + (size_t)e * NDIM * KDIM;
    const int tRow = tid >> 3;
    const int tCol = tid & 7;
    const float* aBase = inp  + (size_t)m0 * KDIM + tCol * 4;
    const float* bBase = wexp + (size_t)n0 * KDIM + tCol * 4;

    const int wave = tid >> 6;
    const int lane = tid & 63;
    const int wm   = wave & 1;
    const int wn   = wave >> 1;
    const int r16  = lane & 15;
    const int quad = lane >> 4;

    f32x4 acc[8][4] = {};
    float4 ra[4], rb[4];
    #pragma unroll
    for (int i = 0; i < 4; ++i) {
        const int row = i * 64 + tRow;
        ra[i] = *(const float4*)(aBase + (size_t)row * KDIM);
        rb[i] = *(const float4*)(bBase + (size_t)row * KDIM);
    }

    const int KSTEPS = KDIM / 32;
    for (int kt = 0; kt < KSTEPS; ++kt) {
        __syncthreads();
        #pragma unroll
        for (int i = 0; i < 4; ++i) {
            const int row = i * 64 + tRow;
            *(uint2*)&sA[row * LDSS + tCol * 4] = pk4(ra[i]);
            *(uint2*)&sB[row * LDSS + tCol * 4] = pk4(rb[i]);
        }
        __syncthreads();
        if (kt + 1 < KSTEPS) {
            const int koff = (kt + 1) * 32;
            #pragma unroll
            for (int i = 0; i < 4; ++i) {
                const int row = i * 64 + tRow;
                ra[i] = *(const float4*)(aBase + (size_t)row * KDIM + koff);
                rb[i] = *(const float4*)(bBase + (size_t)row * KDIM + koff);
            }
        }
        short8 bfr[4];
        #pragma unroll
        for (int nt = 0; nt < 4; ++nt)
            bfr[nt] = *(const short8*)&sB[(wn * 64 + nt * 16 + r16) * LDSS + quad * 8];
        #pragma unroll
        for (int mt = 0; mt < 8; ++mt) {
            const short8 af = *(const short8*)&sA[(wm * 128 + mt * 16 + r16) * LDSS + quad * 8];
            #pragma unroll
            for (int nt = 0; nt < 4; ++nt)
                acc[mt][nt] = __builtin_amdgcn_mfma_f32_16x16x32_bf16(
                    af, bfr[nt], acc[mt][nt], 0, 0, 0);
        }
    }

    #pragma unroll
    for (int nt = 0; nt < 4; ++nt) {
        const int n = n0 + wn * 64 + nt * 16 + r16;
        const float bv = bias[(size_t)e * NDIM + n];
        #pragma unroll
        for (int mt = 0; mt < 8; ++mt) {
            #pragma unroll
            for (int r = 0; r < 4; ++r) {
                const int m = m0 + wm * 128 + mt * 16 + quad * 4 + r;
                out[(size_t)m * NDIM + n] = acc[mt][nt][r] + bv;
            }
        }
    }
}

extern "C" void kernel_launch(void* const* d_in, const int* in_sizes, int n_in,
                              void* d_out, int out_size, void* d_ws, size_t ws_size,
                              hipStream_t stream) {
    const float* inp    = (const float*)d_in[0];
    const float* weight = (const float*)d_in[1];
    const float* bias   = (const float*)d_in[2];
    const int*   cnt    = (const int*)d_in[3];
    float* out = (float*)d_out;

    if (d_ws != nullptr && ws_size >= WS_NEED) {
        const int rows = TOK + NEXP * NDIM;   // 139264 source rows
        hipLaunchKernelGGL(convert_bf16, dim3(rows), dim3(256), 0, stream,
                           inp, weight, (char*)d_ws);
        const int grid = (TOK / BM) * (NDIM / BN);   // 1024
        hipLaunchKernelGGL(moe_gemm, dim3(grid), dim3(512), 0, stream,
                           (const char*)d_ws, bias, cnt, out);
    } else {
        const int grid = (TOK / BM) * (NDIM / BN);   // 1024
        hipLaunchKernelGGL(moe_gemm_fb, dim3(grid), dim3(512), 0, stream,
                           inp, weight, bias, cnt, out);
    }
}

// Round 3
// 1553.919 us; speedup vs baseline: 1.1428x; 1.1428x over previous
//
#include <hip/hip_runtime.h>
#include <hip/hip_bf16.h>

// Grouped GEMM (FMoE expert linear), MI355X/gfx950.
// out[t,n] = sum_k inp[t,k] * weight[e(t),n,k] + bias[e(t),n]
// T=8192, K=2048, N=8192, E=16, equal 512-token groups.
//
// R3: double-buffered single-raw-barrier pipeline.
// R2 post-mortem: dur_us = ~1370us constant harness fills + kernel (<675us,
// since fills dominate the rocprof top-5). R0/R1 kernel part ~366-406us.
// Their bottleneck: single-buffered LDS + 2 __syncthreads per BK=32 step
// fully serializes {MFMA} vs {convert+ds_write} (m233 regime).
// Fix: LDS double-buffer, ONE raw s_barrier per K-step, no vmcnt drain at the
// barrier (loads for tile t+2 fly across it), convert+write overlaps MFMA.
// Packed-swizzled LDS tile (2 rows/128B line, chunk XOR) -> 64 KB total ->
// 2 blocks/CU co-resident for cross-block latency hiding.

#define TOK   8192
#define KDIM  2048
#define NDIM  8192
#define NEXP  16

#define BM 256
#define BN 256
#define BK 32
#define NKT (KDIM / BK)        // 64 k-steps
#define TILEB 16384            // 256 rows x 32 bf16 = 16 KB per matrix per buf

typedef __attribute__((ext_vector_type(8))) short short8;
typedef __attribute__((ext_vector_type(4))) float f32x4;

// fp32 -> bf16 (round-half-up) pair pack: 1 add per elem + 1 v_perm per pair.
__device__ __forceinline__ unsigned pk2(float lo, float hi) {
    unsigned ul = __float_as_uint(lo) + 0x8000u;
    unsigned uh = __float_as_uint(hi) + 0x8000u;
    return __builtin_amdgcn_perm(uh, ul, 0x07060302u);
}
// 8 floats (2 float4) -> one 16B chunk of 8 bf16
__device__ __forceinline__ uint4 pkchunk(float4 x, float4 y) {
    uint4 o;
    o.x = pk2(x.x, x.y); o.y = pk2(x.z, x.w);
    o.z = pk2(y.x, y.y); o.w = pk2(y.z, y.w);
    return o;
}

// LDS tile layout: logical [256 rows][32 bf16]; two rows packed per 128B line,
// 16B chunks XOR-swizzled within the line. Bijective; same fn for write+read;
// conflict-free for both the staging ds_write_b128 and the fragment
// ds_read_b128 (each 16-lane quarter touches every bank <=2x = free, m136).
__device__ __forceinline__ int ldsoff(int row, int c) {
    const int L    = row >> 1;                 // 128B line 0..127
    const int slot = ((row & 1) << 2) | c;     // 16B slot 0..7
    return L * 128 + ((slot ^ (L & 7)) << 4);
}

#define LOADG(dst, p0, p1, kt_) do {                         \
    dst[0] = *(const float4*)((p0) + (kt_) * BK);            \
    dst[1] = *(const float4*)((p0) + (kt_) * BK + 4);        \
    dst[2] = *(const float4*)((p1) + (kt_) * BK);            \
    dst[3] = *(const float4*)((p1) + (kt_) * BK + 4);        \
} while (0)

__global__ __launch_bounds__(512) void moe_gemm(
    const float* __restrict__ inp,
    const float* __restrict__ weight,
    const float* __restrict__ bias,
    const int*   __restrict__ cnt,
    float*       __restrict__ out)
{
    // [buf][matrix (0=A,1=B)][bytes]
    __shared__ __attribute__((aligned(16))) char lds[2][2][TILEB];   // 64 KB

    const int tid = threadIdx.x;
    const int b   = blockIdx.x;

    // XCD-aware swizzle over 1024 blocks = 8 xcd * (16 e * 4 nl * 2 mi);
    // m innermost so the 2 m-blocks sharing a weight panel are dispatch-adjacent.
    const int x  = b & 7;
    const int j  = b >> 3;
    const int e  = j >> 3;
    const int t  = j & 7;
    const int nl = t >> 1;
    const int mi = t & 1;
    const int ntile = x * 4 + nl;    // 0..31

    int m_start = 0;
    for (int i = 0; i < e; ++i) m_start += cnt[i];
    const int m0 = m_start + mi * BM;      // harness: 512/expert, 256-aligned
    const int n0 = ntile * BN;

    // staging: tile = 256 rows x 4 chunks(16B bf16 = 8 fp32) = 1024 chunks;
    // 512 threads x 2 chunks. Chunk id = i*512 + tid -> (row, c).
    const int ch0 = tid, ch1 = 512 + tid;
    const int r0 = ch0 >> 2, c0 = ch0 & 3;
    const int r1 = ch1 >> 2, c1 = ch1 & 3;
    const float* pA0 = inp + (size_t)(m0 + r0) * KDIM + c0 * 8;
    const float* pA1 = inp + (size_t)(m0 + r1) * KDIM + c1 * 8;
    const float* wexp = weight + (size_t)e * NDIM * KDIM;
    const float* pB0 = wexp + (size_t)(n0 + r0) * KDIM + c0 * 8;
    const float* pB1 = wexp + (size_t)(n0 + r1) * KDIM + c1 * 8;
    const int w0 = ldsoff(r0, c0);
    const int w1 = ldsoff(r1, c1);

    // wave mapping: 8 waves 2(m) x 4(n), wave tile 128x64, acc[8][4]
    const int wave = tid >> 6;
    const int lane = tid & 63;
    const int wm   = wave & 1;
    const int wn   = wave >> 1;
    const int r16  = lane & 15;
    const int quad = lane >> 4;

    int aoff[8], boff[4];
    #pragma unroll
    for (int mt = 0; mt < 8; ++mt) aoff[mt] = ldsoff(wm * 128 + mt * 16 + r16, quad);
    #pragma unroll
    for (int nt = 0; nt < 4; ++nt) boff[nt] = ldsoff(wn * 64 + nt * 16 + r16, quad);

    f32x4 acc[8][4] = {};
    float4 Ag[4], Bg[4];

    // ---- prologue: stage tile 0 into buf0; issue tile-1 loads ----
    LOADG(Ag, pA0, pA1, 0); LOADG(Bg, pB0, pB1, 0);
    *(uint4*)(&lds[0][0][0] + w0) = pkchunk(Ag[0], Ag[1]);
    *(uint4*)(&lds[0][0][0] + w1) = pkchunk(Ag[2], Ag[3]);
    *(uint4*)(&lds[0][1][0] + w0) = pkchunk(Bg[0], Bg[1]);
    *(uint4*)(&lds[0][1][0] + w1) = pkchunk(Bg[2], Bg[3]);
    LOADG(Ag, pA0, pA1, 1); LOADG(Bg, pB0, pB1, 1);
    asm volatile("s_waitcnt lgkmcnt(0)" ::: "memory");
    __builtin_amdgcn_s_barrier();
    __builtin_amdgcn_sched_barrier(0);

    // per K-step: read buf RD + 32 MFMA; write tile kt+1 -> buf WR (no reader
    // conflict); issue loads kt+2 (fly over the barrier, ~1 K-step of latency
    // hiding); lgkmcnt(0) only (NO vmcnt drain) before raw s_barrier.
#define ITER(RD, WR, kt_, DOLOAD) do {                                        \
    short8 bfr[4], afr[8];                                                    \
    _Pragma("unroll")                                                         \
    for (int nt = 0; nt < 4; ++nt)                                            \
        bfr[nt] = *(const short8*)(&lds[RD][1][0] + boff[nt]);                \
    _Pragma("unroll")                                                         \
    for (int mt = 0; mt < 8; ++mt)                                            \
        afr[mt] = *(const short8*)(&lds[RD][0][0] + aoff[mt]);                \
    __builtin_amdgcn_s_setprio(1);                                            \
    _Pragma("unroll")                                                         \
    for (int mt = 0; mt < 8; ++mt)                                            \
        _Pragma("unroll")                                                     \
        for (int nt = 0; nt < 4; ++nt)                                        \
            acc[mt][nt] = __builtin_amdgcn_mfma_f32_16x16x32_bf16(            \
                afr[mt], bfr[nt], acc[mt][nt], 0, 0, 0);                      \
    __builtin_amdgcn_s_setprio(0);                                            \
    __builtin_amdgcn_sched_barrier(0);                                        \
    *(uint4*)(&lds[WR][0][0] + w0) = pkchunk(Ag[0], Ag[1]);                   \
    *(uint4*)(&lds[WR][0][0] + w1) = pkchunk(Ag[2], Ag[3]);                   \
    *(uint4*)(&lds[WR][1][0] + w0) = pkchunk(Bg[0], Bg[1]);                   \
    *(uint4*)(&lds[WR][1][0] + w1) = pkchunk(Bg[2], Bg[3]);                   \
    __builtin_amdgcn_sched_barrier(0);                                        \
    if (DOLOAD) {                                                             \
        LOADG(Ag, pA0, pA1, (kt_) + 2);                                       \
        LOADG(Bg, pB0, pB1, (kt_) + 2);                                       \
    }                                                                         \
    asm volatile("s_waitcnt lgkmcnt(0)" ::: "memory");                        \
    __builtin_amdgcn_s_barrier();                                             \
    __builtin_amdgcn_sched_barrier(0);                                        \
} while (0)

    // kt = 0..61 in ping-pong pairs, kt = 62 (last staging iter), kt = 63 tail
    for (int kt = 0; kt < NKT - 2; kt += 2) {
        ITER(0, 1, kt,     true);
        ITER(1, 0, kt + 1, true);
    }
    ITER(0, 1, NKT - 2, false);   // computes tile 62, stages tile 63 -> buf1

    // ---- final K-step: compute-only on buf1 ----
    {
        short8 bfr[4], afr[8];
        #pragma unroll
        for (int nt = 0; nt < 4; ++nt)
            bfr[nt] = *(const short8*)(&lds[1][1][0] + boff[nt]);
        #pragma unroll
        for (int mt = 0; mt < 8; ++mt)
            afr[mt] = *(const short8*)(&lds[1][0][0] + aoff[mt]);
        __builtin_amdgcn_s_setprio(1);
        #pragma unroll
        for (int mt = 0; mt < 8; ++mt)
            #pragma unroll
            for (int nt = 0; nt < 4; ++nt)
                acc[mt][nt] = __builtin_amdgcn_mfma_f32_16x16x32_bf16(
                    afr[mt], bfr[nt], acc[mt][nt], 0, 0, 0);
        __builtin_amdgcn_s_setprio(0);
    }
#undef ITER

    // epilogue: C/D layout col=lane&15 (n), row=quad*4+reg (m); add bias
    #pragma unroll
    for (int nt = 0; nt < 4; ++nt) {
        const int n = n0 + wn * 64 + nt * 16 + r16;
        const float bv = bias[(size_t)e * NDIM + n];
        #pragma unroll
        for (int mt = 0; mt < 8; ++mt) {
            #pragma unroll
            for (int r = 0; r < 4; ++r) {
                const int m = m0 + wm * 128 + mt * 16 + quad * 4 + r;
                out[(size_t)m * NDIM + n] = acc[mt][nt][r] + bv;
            }
        }
    }
}

extern "C" void kernel_launch(void* const* d_in, const int* in_sizes, int n_in,
                              void* d_out, int out_size, void* d_ws, size_t ws_size,
                              hipStream_t stream) {
    const float* inp    = (const float*)d_in[0];
    const float* weight = (const float*)d_in[1];
    const float* bias   = (const float*)d_in[2];
    const int*   cnt    = (const int*)d_in[3];
    float* out = (float*)d_out;

    const int grid = (TOK / BM) * (NDIM / BN);   // 32 * 32 = 1024
    hipLaunchKernelGGL(moe_gemm, dim3(grid), dim3(512), 0, stream,
                       inp, weight, bias, cnt, out);
}